// Round 8
// baseline (253.310 us; speedup 1.0000x reference)
//
#include <hip/hip_runtime.h>
#include <hip/hip_bf16.h>

// Problem constants (match reference)
#define B_ 2
#define T_ 2048
#define D_ 2048
#define H_ 16
#define G_ 4
#define HD_ 128
#define GS_ (H_/G_)

typedef _Float16 half8 __attribute__((ext_vector_type(8)));
typedef _Float16 half2_t __attribute__((ext_vector_type(2)));
typedef float f32x4 __attribute__((ext_vector_type(4)));
typedef float f32x16 __attribute__((ext_vector_type(16)));
typedef int int4_t __attribute__((ext_vector_type(4)));

// Combined KV tile image: per (b,g,tile64): [K: 64 rows x 136 f16 (128 data + 8 pad)]
// then [V^T: 128 rows x 72 f16 (64 data + 8 pad)]. 17408 + 18432 = 35840 bytes.
#define KV_TILE_BYTES 35840
#define KROW_F16 136
#define VROW_F16 72
#define VBASE_F16 8704   // 17408 bytes / 2

// ---------------- fused vectorized fp32 -> fp16 conversion (x, Wq, Wk, Wv, Wo) ----------------
// granule = 8 elements. Segment cumulative bounds are compile-time constants.
#define C0_ 1048576   // x:  8388608/8
#define C1_ 1572864   // +Wq 4194304/8
#define C2_ 1703936   // +Wk 1048576/8
#define C3_ 1835008   // +Wv 1048576/8
#define C4_ 2359296   // +Wo 4194304/8
__global__ void cvt_all(const float* __restrict__ sx, const float* __restrict__ sq,
                        const float* __restrict__ sk, const float* __restrict__ sv,
                        const float* __restrict__ so,
                        _Float16* __restrict__ dx, _Float16* __restrict__ dq,
                        _Float16* __restrict__ dk, _Float16* __restrict__ dv,
                        _Float16* __restrict__ dw) {
    int g = blockIdx.x * blockDim.x + threadIdx.x;
    int stride = blockDim.x * gridDim.x;
    for (; g < C4_; g += stride) {
        const float* src; _Float16* dst; int local;
        if (g < C0_)      { src = sx; dst = dx; local = g; }
        else if (g < C1_) { src = sq; dst = dq; local = g - C0_; }
        else if (g < C2_) { src = sk; dst = dk; local = g - C1_; }
        else if (g < C3_) { src = sv; dst = dv; local = g - C2_; }
        else              { src = so; dst = dw; local = g - C3_; }
        f32x4 a = *((const f32x4*)src + local * 2);
        f32x4 b = *((const f32x4*)src + local * 2 + 1);
        half8 hv;
        hv[0] = (_Float16)a[0]; hv[1] = (_Float16)a[1];
        hv[2] = (_Float16)a[2]; hv[3] = (_Float16)a[3];
        hv[4] = (_Float16)b[0]; hv[5] = (_Float16)b[1];
        hv[6] = (_Float16)b[2]; hv[7] = (_Float16)b[3];
        *((half8*)dst + local) = hv;
    }
}

// ---------------- RoPE tables: cos/sin (T_, 64) ----------------
__global__ void rope_tables_k(float* __restrict__ cosT, float* __restrict__ sinT) {
    int i = blockIdx.x * blockDim.x + threadIdx.x; // T_*64 threads
    int t = i >> 6, l = i & 63;
    float inv_freq = powf(10000.0f, -((float)(2 * l)) / 128.0f);
    float a = (float)t * inv_freq;
    cosT[i] = cosf(a);
    sinT[i] = sinf(a);
}

// ---------------- Tiled TN GEMM, 64x128 tile (occupancy-oriented) ----------------
// C[M,N] = A[M,K] * B[N,K]^T, f16 in / f32 out. BM=64, BN=128, BK=32, 4 waves.
// Wave w: wm=w&1 (32-row half), wn=w>>1 (64-col half); acc 2x4 of 16x16x32 MFMA.
// 1D grid nwg = nxt*nyt, nwg % 8 == 0; bijective XCD-chunk swizzle, y-fastest
// within chunk (each XCD keeps an A row-band in L2, streams B panels once).
__global__ void __launch_bounds__(256, 6) gemm_tile64(const _Float16* __restrict__ A,
                                                      const _Float16* __restrict__ B0,
                                                      float* __restrict__ C0, int n0t,
                                                      const _Float16* __restrict__ B1,
                                                      float* __restrict__ C1, int n1t,
                                                      const _Float16* __restrict__ B2,
                                                      float* __restrict__ C2, int n2t,
                                                      int Kd, int nyt) {
    __shared__ _Float16 sA[64 * 32];    // 4 KB
    __shared__ _Float16 sB[128 * 32];   // 8 KB

    int nwg = gridDim.x;
    int id = blockIdx.x;
    int wg = (id & 7) * (nwg >> 3) + (id >> 3);   // XCD-chunked bijective remap
    int by = wg % nyt;
    int bx = wg / nyt;

    int tid = threadIdx.x;
    int w = tid >> 6, lane = tid & 63;
    int l15 = lane & 15, g4 = lane >> 4;
    int wm = w & 1, wn = w >> 1;

    const _Float16* Bsel;
    float* Csel;
    int ldc, cb;
    if (by < n0t)            { Bsel = B0; Csel = C0; ldc = n0t * 128; cb = by; }
    else if (by < n0t + n1t) { Bsel = B1; Csel = C1; ldc = n1t * 128; cb = by - n0t; }
    else                     { Bsel = B2; Csel = C2; ldc = n2t * 128; cb = by - n0t - n1t; }

    const _Float16* Ab = A + (size_t)(bx * 64) * Kd;
    const _Float16* Bb = Bsel + (size_t)(cb * 128) * Kd;

    // staging geometry: granule s (16B) -> row s>>2, kchunk s&3
    int sb1 = tid + 256;
    size_t gaA  = (size_t)(tid >> 2) * Kd + (tid & 3) * 8;
    size_t gaB1 = (size_t)(sb1 >> 2) * Kd + (sb1 & 3) * 8;
    _Float16* dA  = sA + (size_t)tid * 8;
    _Float16* dB0 = sB + (size_t)tid * 8;
    _Float16* dB1 = sB + (size_t)sb1 * 8;

    #define STAGE(K0)                                                                      \
        do {                                                                               \
            __builtin_amdgcn_global_load_lds(                                              \
                (const __attribute__((address_space(1))) unsigned int*)(Ab + gaA + (K0)),  \
                (__attribute__((address_space(3))) unsigned int*)dA, 16, 0, 0);            \
            __builtin_amdgcn_global_load_lds(                                              \
                (const __attribute__((address_space(1))) unsigned int*)(Bb + gaA + (K0)),  \
                (__attribute__((address_space(3))) unsigned int*)dB0, 16, 0, 0);           \
            __builtin_amdgcn_global_load_lds(                                              \
                (const __attribute__((address_space(1))) unsigned int*)(Bb + gaB1 + (K0)), \
                (__attribute__((address_space(3))) unsigned int*)dB1, 16, 0, 0);           \
        } while (0)

    f32x4 acc[2][4];
    #pragma unroll
    for (int i = 0; i < 2; i++)
        #pragma unroll
        for (int j = 0; j < 4; j++) acc[i][j] = (f32x4){0.f, 0.f, 0.f, 0.f};

    STAGE(0);

    int nIt = Kd >> 5;
    for (int it = 0; it < nIt; ++it) {
        __syncthreads();   // staging of this tile complete (compiler drains vmcnt)

        half8 af[2], bf[4];
        #pragma unroll
        for (int mi = 0; mi < 2; mi++)
            af[mi] = *(const half8*)&sA[(wm * 32 + mi * 16 + l15) * 32 + g4 * 8];
        #pragma unroll
        for (int ni = 0; ni < 4; ni++)
            bf[ni] = *(const half8*)&sB[(wn * 64 + ni * 16 + l15) * 32 + g4 * 8];

        #pragma unroll
        for (int mi = 0; mi < 2; mi++)
            #pragma unroll
            for (int ni = 0; ni < 4; ni++)
                acc[mi][ni] = __builtin_amdgcn_mfma_f32_16x16x32_f16(af[mi], bf[ni], acc[mi][ni], 0, 0, 0);

        if (it + 1 < nIt) {
            __syncthreads();            // all reads done before overwrite
            STAGE((size_t)(it + 1) * 32);
        }
    }
    #undef STAGE

    int rbase = bx * 64 + wm * 32 + g4 * 4;
    int cbase = cb * 128 + wn * 64 + l15;
    #pragma unroll
    for (int mi = 0; mi < 2; mi++)
        #pragma unroll
        for (int r = 0; r < 4; r++) {
            float* crow = Csel + (size_t)(rbase + mi * 16 + r) * ldc + cbase;
            #pragma unroll
            for (int ni = 0; ni < 4; ni++) crow[ni * 16] = acc[mi][ni][r];
        }
}

// ---------------- fused RMSNorm + RoPE (Q and K in one dispatch) ----------------
// Waves 0..65535: Q rows (B*T*H = 65536; write f16 q_h with 1/128 scale).
// Waves 65536..81919: K rows (B*T*G = 16384; f32 in-place).
__global__ void rmsnorm_rope_qk(float* __restrict__ Qf, float* __restrict__ Kf,
                                const float* __restrict__ qw, const float* __restrict__ kw,
                                const float* __restrict__ cosT, const float* __restrict__ sinT,
                                _Float16* __restrict__ qH) {
    int gw = (int)((blockIdx.x * (size_t)blockDim.x + threadIdx.x) >> 6);
    int lane = threadIdx.x & 63;
    bool isQ = gw < (B_ * T_ * H_);
    int row_i = isQ ? gw : gw - (B_ * T_ * H_);
    int heads = isQ ? H_ : G_;
    const float* wv = isQ ? qw : kw;
    float* row = (isQ ? Qf : Kf) + (size_t)row_i * HD_;
    int t = (row_i / heads) % T_;
    float x0 = row[lane];
    float x1 = row[lane + 64];
    float ss = x0 * x0 + x1 * x1;
    #pragma unroll
    for (int off = 1; off < 64; off <<= 1) ss += __shfl_xor(ss, off);
    float inv = rsqrtf(ss * (1.0f / 128.0f) + 1e-6f);
    float n0 = x0 * inv * wv[lane];
    float n1 = x1 * inv * wv[lane + 64];
    float c = cosT[t * 64 + lane];
    float s = sinT[t * 64 + lane];
    float r0 = n0 * c - n1 * s;
    float r1 = n1 * c + n0 * s;
    if (isQ) {
        qH[(size_t)row_i * HD_ + lane]      = (_Float16)(r0 * (1.0f / 128.0f));
        qH[(size_t)row_i * HD_ + lane + 64] = (_Float16)(r1 * (1.0f / 128.0f));
    } else {
        row[lane]      = r0;
        row[lane + 64] = r1;
    }
}

// ---------------- pack K+V into combined padded f16 tile image ----------------
__global__ void __launch_bounds__(256) pack_kv(const float* __restrict__ kf,
                                               const float* __restrict__ vf,
                                               _Float16* __restrict__ img) {
    int bid = blockIdx.x;
    int tile = bid & 31, g = (bid >> 5) & 3, b = bid >> 7;
    int tid = threadIdx.x;
    _Float16* out = img + (size_t)bid * (KV_TILE_BYTES / 2);

    // K part: 64 rows x 17 granules (granule 16 = pad)
    #pragma unroll
    for (int it = 0; it < 5; it++) {
        int gi = tid + 256 * it;
        if (gi < 64 * 17) {
            int key = gi / 17, gr = gi % 17;
            half8 hv = (half8){0, 0, 0, 0, 0, 0, 0, 0};
            if (gr < 16) {
                const float* src = kf + ((size_t)((b * T_ + tile * 64 + key) * G_ + g)) * HD_ + gr * 8;
                #pragma unroll
                for (int j = 0; j < 8; j++) hv[j] = (_Float16)src[j];
            }
            *(half8*)(out + (size_t)gi * 8) = hv;
        }
    }
    // V^T part: 128 rows (d) x 9 granules (granule 8 = pad); strided gather transpose
    #pragma unroll
    for (int it = 0; it < 5; it++) {
        int vi = tid + 256 * it;
        if (vi < 128 * 9) {
            int d = vi / 9, gr = vi % 9;
            half8 hv = (half8){0, 0, 0, 0, 0, 0, 0, 0};
            if (gr < 8) {
                const float* src = vf + ((size_t)((b * T_ + tile * 64 + gr * 8) * G_ + g)) * HD_ + d;
                #pragma unroll
                for (int j = 0; j < 8; j++) hv[j] = (_Float16)src[(size_t)j * (G_ * HD_)];
            }
            *(half8*)(out + VBASE_F16 + (size_t)vi * 8) = hv;
        }
    }
}

// ---------------- causal GQA flash attention v4 ----------------
// 32x32x16 MFMA, swapped QK^T, in-register softmax + P (T12), defer-max (T13).
__global__ void __launch_bounds__(256, 2) attn_mfma4(const _Float16* __restrict__ qh,
                                                     const _Float16* __restrict__ kvimg,
                                                     _Float16* __restrict__ ctx) {
    int id = blockIdx.x;
    int hlf = id >> 8, rr0 = id & 255;
    int qb = hlf ? (15 - (rr0 & 15)) : (rr0 & 15);
    int hb = (rr0 >> 4) | (hlf << 4);
    int h = hb & 15, b = hb >> 4;
    int g = h >> 2;

    int tid = threadIdx.x;
    int w = tid >> 6, lane = tid & 63;
    int l31 = lane & 31, hi = lane >> 5;

    __shared__ __align__(16) char sKV[2][KV_TILE_BYTES];

    int qW = qb * 128 + w * 32;
    int qme = qW + l31;

    half8 qfrag[8];
    {
        const _Float16* qrow = qh + ((size_t)(b * T_ + qme)) * (H_ * HD_) + h * HD_ + hi * 8;
        #pragma unroll
        for (int ks = 0; ks < 8; ks++) qfrag[ks] = *(const half8*)(qrow + ks * 16);
    }

    f32x16 o[4];
    #pragma unroll
    for (int dt2 = 0; dt2 < 4; dt2++)
        #pragma unroll
        for (int r = 0; r < 16; r++) o[dt2][r] = 0.f;
    float m = -INFINITY, lsum = 0.f;

    const char* ibase = (const char*)kvimg + (size_t)((b * 4 + g) * 32) * KV_TILE_BYTES;

    #define STAGE_T(BUF, KT)                                                                       \
        do {                                                                                       \
            const char* src_ = ibase + (size_t)(KT) * KV_TILE_BYTES;                               \
            char* dst_ = &sKV[BUF][0];                                                             \
            _Pragma("unroll")                                                                      \
            for (int i_ = 0; i_ < 9; i_++) {                                                       \
                int c_ = w + 4 * i_;                                                               \
                if (c_ < 35) {                                                                     \
                    __builtin_amdgcn_global_load_lds(                                              \
                        (const __attribute__((address_space(1))) unsigned int*)(src_ + c_ * 1024 + lane * 16), \
                        (__attribute__((address_space(3))) unsigned int*)(dst_ + c_ * 1024 + lane * 16), 16, 0, 0); \
                }                                                                                  \
            }                                                                                      \
        } while (0)

    int nt = 2 * qb + 2;
    int ktmax_w = (qW + 31) >> 6;

    STAGE_T(0, 0);
    int cur = 0;

    for (int kt = 0; kt < nt; kt++) {
        __syncthreads();
        if (kt + 1 < nt) STAGE_T(cur ^ 1, kt + 1);

        if (kt <= ktmax_w) {
            const char* bufK = &sKV[cur][0];
            const char* bufV = &sKV[cur][0] + VBASE_F16 * 2;

            f32x16 stc[2];
            #pragma unroll
            for (int kt2 = 0; kt2 < 2; kt2++)
                #pragma unroll
                for (int r = 0; r < 16; r++) stc[kt2][r] = 0.f;

            __builtin_amdgcn_s_setprio(1);
            #pragma unroll
            for (int ks = 0; ks < 8; ks++) {
                #pragma unroll
                for (int kt2 = 0; kt2 < 2; kt2++) {
                    half8 kfr = *(const half8*)(bufK + (kt2 * 32 + l31) * (KROW_F16 * 2) + ks * 32 + hi * 16);
                    stc[kt2] = __builtin_amdgcn_mfma_f32_32x32x16_f16(kfr, qfrag[ks], stc[kt2], 0, 0, 0);
                }
            }
            __builtin_amdgcn_s_setprio(0);

            #pragma unroll
            for (int kt2 = 0; kt2 < 2; kt2++)
                #pragma unroll
                for (int reg = 0; reg < 16; reg++) {
                    int key = kt * 64 + kt2 * 32 + 8 * (reg >> 2) + 4 * hi + (reg & 3);
                    float v = stc[kt2][reg];
                    stc[kt2][reg] = (key <= qme) ? v : -INFINITY;
                }

            float pmax = -INFINITY;
            #pragma unroll
            for (int kt2 = 0; kt2 < 2; kt2++)
                #pragma unroll
                for (int reg = 0; reg < 16; reg++) pmax = fmaxf(pmax, stc[kt2][reg]);
            pmax = fmaxf(pmax, __shfl_xor(pmax, 32));

            if (__any(!(pmax - m <= 8.0f))) {
                float nm = fmaxf(m, pmax);
                float alpha = __expf(m - nm);
                lsum *= alpha;
                #pragma unroll
                for (int reg = 0; reg < 16; reg++) {
                    float ar = __shfl(alpha, 8 * (reg >> 2) + 4 * hi + (reg & 3));
                    #pragma unroll
                    for (int dt2 = 0; dt2 < 4; dt2++) o[dt2][reg] *= ar;
                }
                m = nm;
            }

            float rsum = 0.f;
            #pragma unroll
            for (int kt2 = 0; kt2 < 2; kt2++)
                #pragma unroll
                for (int reg = 0; reg < 16; reg++) {
                    float e = __expf(stc[kt2][reg] - m);
                    stc[kt2][reg] = e;
                    rsum += e;
                }
            rsum += __shfl_xor(rsum, 32);
            lsum += rsum;

            int pk[16];
            #pragma unroll
            for (int kt2 = 0; kt2 < 2; kt2++)
                #pragma unroll
                for (int oo = 0; oo < 4; oo++)
                    #pragma unroll
                    for (int c = 0; c < 2; c++) {
                        half2_t hp;
                        hp[0] = (_Float16)stc[kt2][4 * oo + 2 * c];
                        hp[1] = (_Float16)stc[kt2][4 * oo + 2 * c + 1];
                        pk[kt2 * 8 + 2 * oo + c] = __builtin_bit_cast(int, hp);
                    }

            __builtin_amdgcn_s_setprio(1);
            #pragma unroll
            for (int ks = 0; ks < 4; ks++) {
                int base = (ks >> 1) * 8 + (ks & 1) * 4;
                int z0 = hi ? pk[base + 0] : pk[base + 2];
                int z1 = hi ? pk[base + 1] : pk[base + 3];
                int xz0 = __shfl_xor(z0, 32);
                int xz1 = __shfl_xor(z1, 32);
                int4_t pi;
                pi[0] = hi ? xz0 : pk[base + 0];
                pi[1] = hi ? xz1 : pk[base + 1];
                pi[2] = hi ? pk[base + 2] : xz0;
                pi[3] = hi ? pk[base + 3] : xz1;
                half8 pfrag = __builtin_bit_cast(half8, pi);
                #pragma unroll
                for (int dt2 = 0; dt2 < 4; dt2++) {
                    half8 vfr = *(const half8*)(bufV + (dt2 * 32 + l31) * (VROW_F16 * 2) + ks * 32 + hi * 16);
                    o[dt2] = __builtin_amdgcn_mfma_f32_32x32x16_f16(pfrag, vfr, o[dt2], 0, 0, 0);
                }
            }
            __builtin_amdgcn_s_setprio(0);
        }
        cur ^= 1;
    }
    #undef STAGE_T

    float invl = 1.0f / lsum;
    #pragma unroll
    for (int reg = 0; reg < 16; reg++) {
        int qrow = 8 * (reg >> 2) + 4 * hi + (reg & 3);
        float ir = __shfl(invl, qrow);
        _Float16* orow = ctx + (size_t)(b * T_ + qW + qrow) * (H_ * HD_) + h * HD_ + l31;
        #pragma unroll
        for (int dt2 = 0; dt2 < 4; dt2++)
            orow[dt2 * 32] = (_Float16)(o[dt2][reg] * ir);
    }
}

// ---------------- launch ----------------
extern "C" void kernel_launch(void* const* d_in, const int* in_sizes, int n_in,
                              void* d_out, int out_size, void* d_ws, size_t ws_size,
                              hipStream_t stream) {
    const float* x   = (const float*)d_in[0];
    const float* Wq  = (const float*)d_in[1];
    const float* Wk  = (const float*)d_in[2];
    const float* Wv  = (const float*)d_in[3];
    const float* Wo  = (const float*)d_in[4];
    const float* qnw = (const float*)d_in[5];
    const float* knw = (const float*)d_in[6];
    float* out = (float*)d_out;

    char* ws = (char*)d_ws;
    size_t off = 0;
    auto alloc = [&](size_t bytes) {
        char* p = ws + off;
        off += (bytes + 255) & ~(size_t)255;
        return p;
    };
    _Float16* x_h  = (_Float16*)alloc((size_t)B_ * T_ * D_ * 2);        // reused as q_h
    _Float16* wq_h = (_Float16*)alloc((size_t)H_ * HD_ * D_ * 2);       // reused as kvimg (with wk_h)
    _Float16* wk_h = (_Float16*)alloc((size_t)G_ * HD_ * D_ * 2);
    _Float16* wv_h = (_Float16*)alloc((size_t)G_ * HD_ * D_ * 2);
    _Float16* wo_h = (_Float16*)alloc((size_t)D_ * H_ * HD_ * 2);
    float* q_f = (float*)alloc((size_t)B_ * T_ * H_ * HD_ * 4);
    float* k_f = (float*)alloc((size_t)B_ * T_ * G_ * HD_ * 4);
    float* v_f = (float*)alloc((size_t)B_ * T_ * G_ * HD_ * 4);
    _Float16* ctx_h = (_Float16*)alloc((size_t)B_ * T_ * H_ * HD_ * 2);
    float* cosT = (float*)alloc((size_t)T_ * 64 * 4);
    float* sinT = (float*)alloc((size_t)T_ * 64 * 4);

    // aliases (lifetimes disjoint):
    _Float16* q_h   = x_h;     // x_h dead after QKV GEMM
    _Float16* kvimg = wq_h;    // wq_h+wk_h dead after QKV GEMM; image = 256*35840 = 9.2 MB

    // fused vectorized conversions + rope tables
    cvt_all<<<2048, 256, 0, stream>>>(x, Wq, Wk, Wv, Wo, x_h, wq_h, wk_h, wv_h, wo_h);
    rope_tables_k<<<(T_ * 64) / 256, 256, 0, stream>>>(cosT, sinT);

    // fused Q+K+V projection: 64x128 tiles, 1536 blocks = 6/CU
    gemm_tile64<<<64 * 24, 256, 0, stream>>>(x_h, wq_h, q_f, 16,
                                             wk_h, k_f, 4,
                                             wv_h, v_f, 4, D_, 24);

    // fused Q+K norm+rope (Q -> f16 with 1/128 scale; K in-place f32)
    // Q rows: B*T*H = 65536, K rows: B*T*G = 16384 -> 81920 waves, 20480 blocks
    rmsnorm_rope_qk<<<(B_ * T_ * (H_ + G_)) / 4, 256, 0, stream>>>(q_f, k_f, qnw, knw, cosT, sinT, q_h);

    // pack K/V into combined padded f16 tile images
    pack_kv<<<256, 256, 0, stream>>>(k_f, v_f, kvimg);

    // causal GQA attention -> ctx (f16)
    attn_mfma4<<<512, 256, 0, stream>>>(q_h, kvimg, ctx_h);

    // output projection: 64x128 tiles, 1024 blocks = 4/CU
    gemm_tile64<<<64 * 16, 256, 0, stream>>>(ctx_h, wo_h, out, 16,
                                             nullptr, nullptr, 0,
                                             nullptr, nullptr, 0, H_ * HD_, 16);
}

// Round 9
// 218.524 us; speedup vs baseline: 1.1592x; 1.1592x over previous
//
#include <hip/hip_runtime.h>
#include <hip/hip_bf16.h>

// Problem constants (match reference)
#define B_ 2
#define T_ 2048
#define D_ 2048
#define H_ 16
#define G_ 4
#define HD_ 128
#define GS_ (H_/G_)

typedef _Float16 half8 __attribute__((ext_vector_type(8)));
typedef _Float16 half2_t __attribute__((ext_vector_type(2)));
typedef float f32x4 __attribute__((ext_vector_type(4)));
typedef float f32x16 __attribute__((ext_vector_type(16)));
typedef int int4_t __attribute__((ext_vector_type(4)));

// Combined KV tile image: per (b,g,tile64): [K: 64 rows x 136 f16 (128 data + 8 pad)]
// then [V^T: 128 rows x 72 f16 (64 data + 8 pad)]. 17408 + 18432 = 35840 bytes.
#define KV_TILE_BYTES 35840
#define KROW_F16 136
#define VROW_F16 72
#define VBASE_F16 8704   // 17408 bytes / 2

// ---------------- fused vectorized fp32 -> fp16 conversion (x, Wq, Wk, Wv, Wo) ----------------
#define C0_ 1048576   // x:  8388608/8
#define C1_ 1572864   // +Wq 4194304/8
#define C2_ 1703936   // +Wk 1048576/8
#define C3_ 1835008   // +Wv 1048576/8
#define C4_ 2359296   // +Wo 4194304/8
__global__ void cvt_all(const float* __restrict__ sx, const float* __restrict__ sq,
                        const float* __restrict__ sk, const float* __restrict__ sv,
                        const float* __restrict__ so,
                        _Float16* __restrict__ dx, _Float16* __restrict__ dq,
                        _Float16* __restrict__ dk, _Float16* __restrict__ dv,
                        _Float16* __restrict__ dw) {
    int g = blockIdx.x * blockDim.x + threadIdx.x;
    int stride = blockDim.x * gridDim.x;
    for (; g < C4_; g += stride) {
        const float* src; _Float16* dst; int local;
        if (g < C0_)      { src = sx; dst = dx; local = g; }
        else if (g < C1_) { src = sq; dst = dq; local = g - C0_; }
        else if (g < C2_) { src = sk; dst = dk; local = g - C1_; }
        else if (g < C3_) { src = sv; dst = dv; local = g - C2_; }
        else              { src = so; dst = dw; local = g - C3_; }
        f32x4 a = *((const f32x4*)src + local * 2);
        f32x4 b = *((const f32x4*)src + local * 2 + 1);
        half8 hv;
        hv[0] = (_Float16)a[0]; hv[1] = (_Float16)a[1];
        hv[2] = (_Float16)a[2]; hv[3] = (_Float16)a[3];
        hv[4] = (_Float16)b[0]; hv[5] = (_Float16)b[1];
        hv[6] = (_Float16)b[2]; hv[7] = (_Float16)b[3];
        *((half8*)dst + local) = hv;
    }
}

// ---------------- RoPE tables: cos/sin (T_, 64) ----------------
__global__ void rope_tables_k(float* __restrict__ cosT, float* __restrict__ sinT) {
    int i = blockIdx.x * blockDim.x + threadIdx.x; // T_*64 threads
    int t = i >> 6, l = i & 63;
    float inv_freq = powf(10000.0f, -((float)(2 * l)) / 128.0f);
    float a = (float)t * inv_freq;
    cosT[i] = cosf(a);
    sinT[i] = sinf(a);
}

// ---------------- Tiled TN GEMM, 128x128 tile, 2-deep counted-vmcnt pipeline ----------------
// C[M,N] = A[M,K] * B[N,K]^T, f16 in / f32 out. BK=32, 4 waves, 64x64 per wave.
// Double-buffered LDS; prologue stages tiles 0,1; per iter: vmcnt(4) [vmcnt(0) on
// last] -> s_barrier -> ds_read+MFMA -> fence -> s_barrier -> STAGE(t+2).
// Loads stay in flight across barriers (T4); no full drain in steady state.
__global__ void __launch_bounds__(256) gemm_tile(const _Float16* __restrict__ A,
                                                 const _Float16* __restrict__ B0,
                                                 float* __restrict__ C0, int n0t,
                                                 const _Float16* __restrict__ B1,
                                                 float* __restrict__ C1, int n1t,
                                                 const _Float16* __restrict__ B2,
                                                 float* __restrict__ C2, int n2t,
                                                 int Kd) {
    __shared__ _Float16 sA[2][128 * 32];
    __shared__ _Float16 sB[2][128 * 32];

    int tid = threadIdx.x;
    int w = tid >> 6, lane = tid & 63;
    int l15 = lane & 15, g4 = lane >> 4;
    int wm = w >> 1, wn = w & 1;

    int y = blockIdx.y;
    const _Float16* Bsel;
    float* Csel;
    int ldc, cb;
    if (y < n0t)            { Bsel = B0; Csel = C0; ldc = n0t * 128; cb = y; }
    else if (y < n0t + n1t) { Bsel = B1; Csel = C1; ldc = n1t * 128; cb = y - n0t; }
    else                    { Bsel = B2; Csel = C2; ldc = n2t * 128; cb = y - n0t - n1t; }

    const _Float16* Ab = A + (size_t)(blockIdx.x * 128) * Kd;
    const _Float16* Bb = Bsel + (size_t)(cb * 128) * Kd;

    // staging geometry: slot s (16B granule) -> row s>>2, kchunk s&3
    int s0 = w * 128 + lane;
    int s1 = s0 + 64;
    size_t ga0 = (size_t)(s0 >> 2) * Kd + (s0 & 3) * 8;
    size_t ga1 = (size_t)(s1 >> 2) * Kd + (s1 & 3) * 8;

    // STAGE(buf, kt): 4 global_load_lds (16B/lane) per thread-quad pattern
    #define STAGE(BUF, K0)                                                                     \
        do {                                                                                   \
            _Float16* a0_ = &sA[BUF][0] + (size_t)(w * 2) * 512;                               \
            _Float16* a1_ = &sA[BUF][0] + (size_t)(w * 2 + 1) * 512;                           \
            _Float16* b0_ = &sB[BUF][0] + (size_t)(w * 2) * 512;                               \
            _Float16* b1_ = &sB[BUF][0] + (size_t)(w * 2 + 1) * 512;                           \
            __builtin_amdgcn_global_load_lds(                                                  \
                (const __attribute__((address_space(1))) unsigned int*)(Ab + ga0 + (K0)),      \
                (__attribute__((address_space(3))) unsigned int*)a0_, 16, 0, 0);               \
            __builtin_amdgcn_global_load_lds(                                                  \
                (const __attribute__((address_space(1))) unsigned int*)(Ab + ga1 + (K0)),      \
                (__attribute__((address_space(3))) unsigned int*)a1_, 16, 0, 0);               \
            __builtin_amdgcn_global_load_lds(                                                  \
                (const __attribute__((address_space(1))) unsigned int*)(Bb + ga0 + (K0)),      \
                (__attribute__((address_space(3))) unsigned int*)b0_, 16, 0, 0);               \
            __builtin_amdgcn_global_load_lds(                                                  \
                (const __attribute__((address_space(1))) unsigned int*)(Bb + ga1 + (K0)),      \
                (__attribute__((address_space(3))) unsigned int*)b1_, 16, 0, 0);               \
        } while (0)

    f32x4 acc[4][4];
    #pragma unroll
    for (int i = 0; i < 4; i++)
        #pragma unroll
        for (int j = 0; j < 4; j++) acc[i][j] = (f32x4){0.f, 0.f, 0.f, 0.f};

    int nIt = Kd >> 5;
    STAGE(0, 0);
    if (nIt > 1) STAGE(1, 32);

    for (int it = 0; it < nIt; ++it) {
        int cur = it & 1;
        // wait for THIS tile's loads (per-wave), keep next tile's 4 in flight
        if (it + 1 < nIt) asm volatile("s_waitcnt vmcnt(4)" ::: "memory");
        else              asm volatile("s_waitcnt vmcnt(0)" ::: "memory");
        __builtin_amdgcn_sched_barrier(0);
        __builtin_amdgcn_s_barrier();          // all waves' tile-it loads landed
        __builtin_amdgcn_sched_barrier(0);

        half8 af[4], bf[4];
        #pragma unroll
        for (int mi = 0; mi < 4; mi++)
            af[mi] = *(const half8*)&sA[cur][(wm * 64 + mi * 16 + l15) * 32 + g4 * 8];
        #pragma unroll
        for (int ni = 0; ni < 4; ni++)
            bf[ni] = *(const half8*)&sB[cur][(wn * 64 + ni * 16 + l15) * 32 + g4 * 8];

        #pragma unroll
        for (int mi = 0; mi < 4; mi++)
            #pragma unroll
            for (int ni = 0; ni < 4; ni++)
                acc[mi][ni] = __builtin_amdgcn_mfma_f32_16x16x32_f16(af[mi], bf[ni], acc[mi][ni], 0, 0, 0);

        __builtin_amdgcn_sched_barrier(0);
        asm volatile("" ::: "memory");         // pin LDS reads above the barrier
        __builtin_amdgcn_s_barrier();          // all waves done reading buf[cur]
        __builtin_amdgcn_sched_barrier(0);
        if (it + 2 < nIt) STAGE(cur, (size_t)(it + 2) * 32);
    }
    #undef STAGE

    int rbase = blockIdx.x * 128 + wm * 64 + g4 * 4;
    int cbase = cb * 128 + wn * 64 + l15;
    #pragma unroll
    for (int mi = 0; mi < 4; mi++)
        #pragma unroll
        for (int r = 0; r < 4; r++) {
            float* crow = Csel + (size_t)(rbase + mi * 16 + r) * ldc + cbase;
            #pragma unroll
            for (int ni = 0; ni < 4; ni++) crow[ni * 16] = acc[mi][ni][r];
        }
}

// ---------------- fused RMSNorm + RoPE (Q and K in one dispatch) ----------------
// Waves 0..65535: Q rows (B*T*H; write f16 q_h with 1/128 scale).
// Waves 65536..81919: K rows (B*T*G; f32 in-place).
__global__ void rmsnorm_rope_qk(float* __restrict__ Qf, float* __restrict__ Kf,
                                const float* __restrict__ qw, const float* __restrict__ kw,
                                const float* __restrict__ cosT, const float* __restrict__ sinT,
                                _Float16* __restrict__ qH) {
    int gw = (int)((blockIdx.x * (size_t)blockDim.x + threadIdx.x) >> 6);
    int lane = threadIdx.x & 63;
    bool isQ = gw < (B_ * T_ * H_);
    int row_i = isQ ? gw : gw - (B_ * T_ * H_);
    int heads = isQ ? H_ : G_;
    const float* wv = isQ ? qw : kw;
    float* row = (isQ ? Qf : Kf) + (size_t)row_i * HD_;
    int t = (row_i / heads) % T_;
    float x0 = row[lane];
    float x1 = row[lane + 64];
    float ss = x0 * x0 + x1 * x1;
    #pragma unroll
    for (int off = 1; off < 64; off <<= 1) ss += __shfl_xor(ss, off);
    float inv = rsqrtf(ss * (1.0f / 128.0f) + 1e-6f);
    float n0 = x0 * inv * wv[lane];
    float n1 = x1 * inv * wv[lane + 64];
    float c = cosT[t * 64 + lane];
    float s = sinT[t * 64 + lane];
    float r0 = n0 * c - n1 * s;
    float r1 = n1 * c + n0 * s;
    if (isQ) {
        qH[(size_t)row_i * HD_ + lane]      = (_Float16)(r0 * (1.0f / 128.0f));
        qH[(size_t)row_i * HD_ + lane + 64] = (_Float16)(r1 * (1.0f / 128.0f));
    } else {
        row[lane]      = r0;
        row[lane + 64] = r1;
    }
}

// ---------------- pack K+V into combined padded f16 tile image ----------------
__global__ void __launch_bounds__(256) pack_kv(const float* __restrict__ kf,
                                               const float* __restrict__ vf,
                                               _Float16* __restrict__ img) {
    int bid = blockIdx.x;
    int tile = bid & 31, g = (bid >> 5) & 3, b = bid >> 7;
    int tid = threadIdx.x;
    _Float16* out = img + (size_t)bid * (KV_TILE_BYTES / 2);

    // K part: 64 rows x 17 granules (granule 16 = pad)
    #pragma unroll
    for (int it = 0; it < 5; it++) {
        int gi = tid + 256 * it;
        if (gi < 64 * 17) {
            int key = gi / 17, gr = gi % 17;
            half8 hv = (half8){0, 0, 0, 0, 0, 0, 0, 0};
            if (gr < 16) {
                const float* src = kf + ((size_t)((b * T_ + tile * 64 + key) * G_ + g)) * HD_ + gr * 8;
                #pragma unroll
                for (int j = 0; j < 8; j++) hv[j] = (_Float16)src[j];
            }
            *(half8*)(out + (size_t)gi * 8) = hv;
        }
    }
    // V^T part: 128 rows (d) x 9 granules (granule 8 = pad); strided gather transpose
    #pragma unroll
    for (int it = 0; it < 5; it++) {
        int vi = tid + 256 * it;
        if (vi < 128 * 9) {
            int d = vi / 9, gr = vi % 9;
            half8 hv = (half8){0, 0, 0, 0, 0, 0, 0, 0};
            if (gr < 8) {
                const float* src = vf + ((size_t)((b * T_ + tile * 64 + gr * 8) * G_ + g)) * HD_ + d;
                #pragma unroll
                for (int j = 0; j < 8; j++) hv[j] = (_Float16)src[(size_t)j * (G_ * HD_)];
            }
            *(half8*)(out + VBASE_F16 + (size_t)vi * 8) = hv;
        }
    }
}

// ---------------- causal GQA flash attention v4 ----------------
// 32x32x16 MFMA, swapped QK^T, in-register softmax + P (T12), defer-max (T13).
__global__ void __launch_bounds__(256, 2) attn_mfma4(const _Float16* __restrict__ qh,
                                                     const _Float16* __restrict__ kvimg,
                                                     _Float16* __restrict__ ctx) {
    int id = blockIdx.x;
    int hlf = id >> 8, rr0 = id & 255;
    int qb = hlf ? (15 - (rr0 & 15)) : (rr0 & 15);
    int hb = (rr0 >> 4) | (hlf << 4);
    int h = hb & 15, b = hb >> 4;
    int g = h >> 2;

    int tid = threadIdx.x;
    int w = tid >> 6, lane = tid & 63;
    int l31 = lane & 31, hi = lane >> 5;

    __shared__ __align__(16) char sKV[2][KV_TILE_BYTES];

    int qW = qb * 128 + w * 32;
    int qme = qW + l31;

    half8 qfrag[8];
    {
        const _Float16* qrow = qh + ((size_t)(b * T_ + qme)) * (H_ * HD_) + h * HD_ + hi * 8;
        #pragma unroll
        for (int ks = 0; ks < 8; ks++) qfrag[ks] = *(const half8*)(qrow + ks * 16);
    }

    f32x16 o[4];
    #pragma unroll
    for (int dt2 = 0; dt2 < 4; dt2++)
        #pragma unroll
        for (int r = 0; r < 16; r++) o[dt2][r] = 0.f;
    float m = -INFINITY, lsum = 0.f;

    const char* ibase = (const char*)kvimg + (size_t)((b * 4 + g) * 32) * KV_TILE_BYTES;

    #define STAGE_T(BUF, KT)                                                                       \
        do {                                                                                       \
            const char* src_ = ibase + (size_t)(KT) * KV_TILE_BYTES;                               \
            char* dst_ = &sKV[BUF][0];                                                             \
            _Pragma("unroll")                                                                      \
            for (int i_ = 0; i_ < 9; i_++) {                                                       \
                int c_ = w + 4 * i_;                                                               \
                if (c_ < 35) {                                                                     \
                    __builtin_amdgcn_global_load_lds(                                              \
                        (const __attribute__((address_space(1))) unsigned int*)(src_ + c_ * 1024 + lane * 16), \
                        (__attribute__((address_space(3))) unsigned int*)(dst_ + c_ * 1024 + lane * 16), 16, 0, 0); \
                }                                                                                  \
            }                                                                                      \
        } while (0)

    int nt = 2 * qb + 2;
    int ktmax_w = (qW + 31) >> 6;

    STAGE_T(0, 0);
    int cur = 0;

    for (int kt = 0; kt < nt; kt++) {
        __syncthreads();
        if (kt + 1 < nt) STAGE_T(cur ^ 1, kt + 1);

        if (kt <= ktmax_w) {
            const char* bufK = &sKV[cur][0];
            const char* bufV = &sKV[cur][0] + VBASE_F16 * 2;

            f32x16 stc[2];
            #pragma unroll
            for (int kt2 = 0; kt2 < 2; kt2++)
                #pragma unroll
                for (int r = 0; r < 16; r++) stc[kt2][r] = 0.f;

            __builtin_amdgcn_s_setprio(1);
            #pragma unroll
            for (int ks = 0; ks < 8; ks++) {
                #pragma unroll
                for (int kt2 = 0; kt2 < 2; kt2++) {
                    half8 kfr = *(const half8*)(bufK + (kt2 * 32 + l31) * (KROW_F16 * 2) + ks * 32 + hi * 16);
                    stc[kt2] = __builtin_amdgcn_mfma_f32_32x32x16_f16(kfr, qfrag[ks], stc[kt2], 0, 0, 0);
                }
            }
            __builtin_amdgcn_s_setprio(0);

            #pragma unroll
            for (int kt2 = 0; kt2 < 2; kt2++)
                #pragma unroll
                for (int reg = 0; reg < 16; reg++) {
                    int key = kt * 64 + kt2 * 32 + 8 * (reg >> 2) + 4 * hi + (reg & 3);
                    float v = stc[kt2][reg];
                    stc[kt2][reg] = (key <= qme) ? v : -INFINITY;
                }

            float pmax = -INFINITY;
            #pragma unroll
            for (int kt2 = 0; kt2 < 2; kt2++)
                #pragma unroll
                for (int reg = 0; reg < 16; reg++) pmax = fmaxf(pmax, stc[kt2][reg]);
            pmax = fmaxf(pmax, __shfl_xor(pmax, 32));

            if (__any(!(pmax - m <= 8.0f))) {
                float nm = fmaxf(m, pmax);
                float alpha = __expf(m - nm);
                lsum *= alpha;
                #pragma unroll
                for (int reg = 0; reg < 16; reg++) {
                    float ar = __shfl(alpha, 8 * (reg >> 2) + 4 * hi + (reg & 3));
                    #pragma unroll
                    for (int dt2 = 0; dt2 < 4; dt2++) o[dt2][reg] *= ar;
                }
                m = nm;
            }

            float rsum = 0.f;
            #pragma unroll
            for (int kt2 = 0; kt2 < 2; kt2++)
                #pragma unroll
                for (int reg = 0; reg < 16; reg++) {
                    float e = __expf(stc[kt2][reg] - m);
                    stc[kt2][reg] = e;
                    rsum += e;
                }
            rsum += __shfl_xor(rsum, 32);
            lsum += rsum;

            int pk[16];
            #pragma unroll
            for (int kt2 = 0; kt2 < 2; kt2++)
                #pragma unroll
                for (int oo = 0; oo < 4; oo++)
                    #pragma unroll
                    for (int c = 0; c < 2; c++) {
                        half2_t hp;
                        hp[0] = (_Float16)stc[kt2][4 * oo + 2 * c];
                        hp[1] = (_Float16)stc[kt2][4 * oo + 2 * c + 1];
                        pk[kt2 * 8 + 2 * oo + c] = __builtin_bit_cast(int, hp);
                    }

            __builtin_amdgcn_s_setprio(1);
            #pragma unroll
            for (int ks = 0; ks < 4; ks++) {
                int base = (ks >> 1) * 8 + (ks & 1) * 4;
                int z0 = hi ? pk[base + 0] : pk[base + 2];
                int z1 = hi ? pk[base + 1] : pk[base + 3];
                int xz0 = __shfl_xor(z0, 32);
                int xz1 = __shfl_xor(z1, 32);
                int4_t pi;
                pi[0] = hi ? xz0 : pk[base + 0];
                pi[1] = hi ? xz1 : pk[base + 1];
                pi[2] = hi ? pk[base + 2] : xz0;
                pi[3] = hi ? pk[base + 3] : xz1;
                half8 pfrag = __builtin_bit_cast(half8, pi);
                #pragma unroll
                for (int dt2 = 0; dt2 < 4; dt2++) {
                    half8 vfr = *(const half8*)(bufV + (dt2 * 32 + l31) * (VROW_F16 * 2) + ks * 32 + hi * 16);
                    o[dt2] = __builtin_amdgcn_mfma_f32_32x32x16_f16(pfrag, vfr, o[dt2], 0, 0, 0);
                }
            }
            __builtin_amdgcn_s_setprio(0);
        }
        cur ^= 1;
    }
    #undef STAGE_T

    float invl = 1.0f / lsum;
    #pragma unroll
    for (int reg = 0; reg < 16; reg++) {
        int qrow = 8 * (reg >> 2) + 4 * hi + (reg & 3);
        float ir = __shfl(invl, qrow);
        _Float16* orow = ctx + (size_t)(b * T_ + qW + qrow) * (H_ * HD_) + h * HD_ + l31;
        #pragma unroll
        for (int dt2 = 0; dt2 < 4; dt2++)
            orow[dt2 * 32] = (_Float16)(o[dt2][reg] * ir);
    }
}

// ---------------- launch ----------------
extern "C" void kernel_launch(void* const* d_in, const int* in_sizes, int n_in,
                              void* d_out, int out_size, void* d_ws, size_t ws_size,
                              hipStream_t stream) {
    const float* x   = (const float*)d_in[0];
    const float* Wq  = (const float*)d_in[1];
    const float* Wk  = (const float*)d_in[2];
    const float* Wv  = (const float*)d_in[3];
    const float* Wo  = (const float*)d_in[4];
    const float* qnw = (const float*)d_in[5];
    const float* knw = (const float*)d_in[6];
    float* out = (float*)d_out;

    char* ws = (char*)d_ws;
    size_t off = 0;
    auto alloc = [&](size_t bytes) {
        char* p = ws + off;
        off += (bytes + 255) & ~(size_t)255;
        return p;
    };
    _Float16* x_h  = (_Float16*)alloc((size_t)B_ * T_ * D_ * 2);        // reused as q_h
    _Float16* wq_h = (_Float16*)alloc((size_t)H_ * HD_ * D_ * 2);       // reused as kvimg (with wk_h)
    _Float16* wk_h = (_Float16*)alloc((size_t)G_ * HD_ * D_ * 2);
    _Float16* wv_h = (_Float16*)alloc((size_t)G_ * HD_ * D_ * 2);
    _Float16* wo_h = (_Float16*)alloc((size_t)D_ * H_ * HD_ * 2);
    float* q_f = (float*)alloc((size_t)B_ * T_ * H_ * HD_ * 4);
    float* k_f = (float*)alloc((size_t)B_ * T_ * G_ * HD_ * 4);
    float* v_f = (float*)alloc((size_t)B_ * T_ * G_ * HD_ * 4);
    _Float16* ctx_h = (_Float16*)alloc((size_t)B_ * T_ * H_ * HD_ * 2);
    float* cosT = (float*)alloc((size_t)T_ * 64 * 4);
    float* sinT = (float*)alloc((size_t)T_ * 64 * 4);

    // aliases (lifetimes disjoint):
    _Float16* q_h   = x_h;     // x_h dead after QKV GEMM
    _Float16* kvimg = wq_h;    // wq_h+wk_h dead after QKV GEMM; image = 256*35840 = 9.2 MB

    // fused vectorized conversions + rope tables
    cvt_all<<<2048, 256, 0, stream>>>(x, Wq, Wk, Wv, Wo, x_h, wq_h, wk_h, wv_h, wo_h);
    rope_tables_k<<<(T_ * 64) / 256, 256, 0, stream>>>(cosT, sinT);

    // fused Q+K+V projection: 128x128 tiles, pipelined staging (x-fastest grid)
    gemm_tile<<<dim3(32, 24), 256, 0, stream>>>(x_h, wq_h, q_f, 16,
                                                wk_h, k_f, 4,
                                                wv_h, v_f, 4, D_);

    // fused Q+K norm+rope (Q -> f16 with 1/128 scale; K in-place f32)
    rmsnorm_rope_qk<<<(B_ * T_ * (H_ + G_)) / 4, 256, 0, stream>>>(q_f, k_f, qnw, knw, cosT, sinT, q_h);

    // pack K/V into combined padded f16 tile images
    pack_kv<<<256, 256, 0, stream>>>(k_f, v_f, kvimg);

    // causal GQA attention -> ctx (f16)
    attn_mfma4<<<512, 256, 0, stream>>>(q_h, kvimg, ctx_h);

    // output projection: 128x128 tiles, pipelined staging
    gemm_tile<<<dim3(32, 16), 256, 0, stream>>>(ctx_h, wo_h, out, 16,
                                                nullptr, nullptr, 0,
                                                nullptr, nullptr, 0, H_ * HD_);
}